// Round 5
// baseline (505.855 us; speedup 1.0000x reference)
//
#include <hip/hip_runtime.h>
#include <hip/hip_bf16.h>

typedef __attribute__((ext_vector_type(4))) float f32x4;
typedef __attribute__((ext_vector_type(8))) short short8;

#define DEV __device__ __forceinline__

DEV short f2bf(float f) {
    union { float f; unsigned u; } a; a.f = f;
    unsigned r = a.u + 0x7fffu + ((a.u >> 16) & 1u);
    return (short)(r >> 16);
}

DEV float bf2f(short s) {
    union { unsigned u; float f; } a;
    a.u = ((unsigned)(unsigned short)s) << 16;
    return a.f;
}

// packed f32x2 -> bf16x2 (low = a, high = b), RTNE in HW
DEV unsigned cvt_pk_bf16(float a, float b) {
    unsigned r;
    asm("v_cvt_pk_bf16_f32 %0, %1, %2" : "=v"(r) : "v"(a), "v"(b));
    return r;
}

DEV float exp2_fast(float x) { return __builtin_amdgcn_exp2f(x); }

// async 16B global -> LDS (linear dest, per-lane source)
DEV void gload16(const short* g, short* l) {
    __builtin_amdgcn_global_load_lds(
        (__attribute__((address_space(1))) void*)g,
        (__attribute__((address_space(3))) void*)l, 16, 0, 0);
}

DEV float gelu_f(float x) {
    float u = 0.7978845608028654f * (x + 0.044715f * x * x * x);
    float e = __expf(2.0f * u);
    float t = 1.0f - 2.0f / (e + 1.0f);   // tanh(u)
    return 0.5f * x * (1.0f + t);
}

// ---------------- LayerNorm: fp32 in -> bf16 out, D=512, wave per row ----------------
__global__ __launch_bounds__(256) void ln_kernel(const float* __restrict__ x,
                                                 const float* __restrict__ scale,
                                                 const float* __restrict__ offset,
                                                 short* __restrict__ out) {
    const int wid = threadIdx.x >> 6, lane = threadIdx.x & 63;
    const long row = (long)blockIdx.x * 4 + wid;
    const float* xr = x + row * 512;
    f32x4 v0 = *(const f32x4*)&xr[lane * 8];
    f32x4 v1 = *(const f32x4*)&xr[lane * 8 + 4];
    float s = 0.f, sq = 0.f;
#pragma unroll
    for (int i = 0; i < 4; i++) {
        s += v0[i] + v1[i];
        sq += v0[i] * v0[i] + v1[i] * v1[i];
    }
#pragma unroll
    for (int m = 1; m < 64; m <<= 1) { s += __shfl_xor(s, m); sq += __shfl_xor(sq, m); }
    float mean = s * (1.0f / 512.0f);
    float var = sq * (1.0f / 512.0f) - mean * mean;
    float inv = rsqrtf(var + 1e-5f);
    f32x4 sc0 = *(const f32x4*)&scale[lane * 8];
    f32x4 sc1 = *(const f32x4*)&scale[lane * 8 + 4];
    f32x4 of0 = *(const f32x4*)&offset[lane * 8];
    f32x4 of1 = *(const f32x4*)&offset[lane * 8 + 4];
    short8 o;
#pragma unroll
    for (int i = 0; i < 4; i++) {
        o[i]     = f2bf((v0[i] - mean) * inv * sc0[i] + of0[i]);
        o[4 + i] = f2bf((v1[i] - mean) * inv * sc1[i] + of1[i]);
    }
    *(short8*)&out[row * 512 + lane * 8] = o;
}

// ---------------- Fused weight prep: 6 transposes + bias concat in ONE launch ----------------
__global__ __launch_bounds__(256) void prep_kernel(const float* __restrict__ wq,
                                                   const float* __restrict__ wk,
                                                   const float* __restrict__ wv,
                                                   const float* __restrict__ wo,
                                                   const float* __restrict__ w1,
                                                   const float* __restrict__ w2,
                                                   const float* __restrict__ bq,
                                                   const float* __restrict__ bk,
                                                   const float* __restrict__ bv,
                                                   short* __restrict__ wqkvt,
                                                   short* __restrict__ wot,
                                                   short* __restrict__ w1t,
                                                   short* __restrict__ w2t,
                                                   float* __restrict__ bqkv) {
    const int bid = blockIdx.x;
    if (bid == 768) {
        for (int i = threadIdx.x; i < 512; i += 256) {
            bqkv[i] = bq[i]; bqkv[512 + i] = bk[i]; bqkv[1024 + i] = bv[i];
        }
        return;
    }
    const float* src; short* dst; int Kd, N, kt, nt;
    if (bid < 256) {
        Kd = 512; N = 512;
        const int which = bid >> 6, local = bid & 63;
        kt = local & 7; nt = local >> 3;
        if (which == 0)      { src = wq; dst = wqkvt; }
        else if (which == 1) { src = wk; dst = wqkvt + 512 * 512; }
        else if (which == 2) { src = wv; dst = wqkvt + 2 * 512 * 512; }
        else                 { src = wo; dst = wot; }
    } else if (bid < 512) {
        src = w1; dst = w1t; Kd = 512; N = 2048;
        const int local = bid - 256; kt = local & 7; nt = local >> 3;
    } else {
        src = w2; dst = w2t; Kd = 2048; N = 512;
        const int local = bid - 512; kt = local & 31; nt = local >> 5;
    }
    __shared__ float tile[64][65];
    const int k0 = kt * 64, n0 = nt * 64;
    const int tid = threadIdx.x;
#pragma unroll
    for (int ld = 0; ld < 4; ld++) {
        int li = ld * 1024 + tid * 4;
        int r = li >> 6, c = li & 63;
        f32x4 tv = *(const f32x4*)&src[(long)(k0 + r) * N + n0 + c];
        tile[r][c] = tv[0]; tile[r][c + 1] = tv[1];
        tile[r][c + 2] = tv[2]; tile[r][c + 3] = tv[3];
    }
    __syncthreads();
#pragma unroll
    for (int st = 0; st < 2; st++) {
        int li = st * 2048 + tid * 8;
        int r = li >> 6, c = li & 63;
        short8 o;
#pragma unroll
        for (int i = 0; i < 8; i++) o[i] = f2bf(tile[c + i][r]);
        *(short8*)&dst[(long)(n0 + r) * Kd + k0 + c] = o;
    }
}

// ---------------- GEMM: C[M][N] = A[M][Kd] @ Bt[N][Kd]^T + bias (+gelu)(+resid) ----------------
// m97 pattern: global_load_lds(16B) into linear [128][64] LDS; T2 swizzle via
// inverse-swizzled per-lane SOURCE column + swizzled ds_read column.
template <bool GELU_ACT, bool OUT_BF16, bool RESID>
__global__ __launch_bounds__(256) void gemm_bt(const short* __restrict__ A,
                                               const short* __restrict__ Bt,
                                               const float* __restrict__ bias,
                                               const float* __restrict__ resid,
                                               void* __restrict__ Cout,
                                               int M, int N, int Kd) {
    __shared__ short Asm[128][64];
    __shared__ short Bsm[128][64];
    const int tid = threadIdx.x;
    const int wid = tid >> 6, lane = tid & 63;
    const int lr = lane & 15, lg = lane >> 4;
    const int row0 = blockIdx.x * 128, col0 = blockIdx.y * 128;
    const int wm = (wid >> 1) * 64, wn = (wid & 1) * 64;

    f32x4 acc[4][4];
#pragma unroll
    for (int m = 0; m < 4; m++)
#pragma unroll
        for (int n = 0; n < 4; n++)
#pragma unroll
            for (int j = 0; j < 4; j++) acc[m][n][j] = 0.f;

    const int swr = (lr & 7) << 3;   // frag-read column swizzle

    for (int k0 = 0; k0 < Kd; k0 += 64) {
#pragma unroll
        for (int ld = 0; ld < 4; ld++) {
            int off = ld * 2048 + tid * 8;      // dest short offset (linear in tid)
            int r = off >> 6, c = off & 63;
            int sc = c ^ ((r & 7) << 3);        // inverse-swizzled source column
            gload16(&A[(long)(row0 + r) * Kd + k0 + sc], &Asm[0][0] + off);
            gload16(&Bt[(long)(col0 + r) * Kd + k0 + sc], &Bsm[0][0] + off);
        }
        __syncthreads();   // drains vmcnt -> LDS tiles ready
#pragma unroll
        for (int kk = 0; kk < 64; kk += 32) {
            short8 af[4], bf[4];
#pragma unroll
            for (int m = 0; m < 4; m++) af[m] = *(const short8*)&Asm[wm + m * 16 + lr][(kk + lg * 8) ^ swr];
#pragma unroll
            for (int n = 0; n < 4; n++) bf[n] = *(const short8*)&Bsm[wn + n * 16 + lr][(kk + lg * 8) ^ swr];
#pragma unroll
            for (int m = 0; m < 4; m++)
#pragma unroll
                for (int n = 0; n < 4; n++)
                    acc[m][n] = __builtin_amdgcn_mfma_f32_16x16x32_bf16(af[m], bf[n], acc[m][n], 0, 0, 0);
        }
        __syncthreads();
    }

#pragma unroll
    for (int m = 0; m < 4; m++) {
#pragma unroll
        for (int n = 0; n < 4; n++) {
#pragma unroll
            for (int j = 0; j < 4; j++) {
                int r = row0 + wm + m * 16 + lg * 4 + j;
                int c = col0 + wn + n * 16 + lr;
                float v = acc[m][n][j] + bias[c];
                if constexpr (GELU_ACT) v = gelu_f(v);
                if constexpr (RESID) v += resid[(long)r * N + c];
                if constexpr (OUT_BF16) ((short*)Cout)[(long)r * N + c] = f2bf(v);
                else                    ((float*)Cout)[(long)r * N + c] = v;
            }
        }
    }
}

// ---------------- Flash attention v4: split-KV + partials ----------------
// grid (32, 16, 2): 128 q-rows x (b,h) x KV-split(2048 keys). 4 waves x 32 rows.
// Writes un-normalized O (fp32) + per-row m,l (log2 domain) for the merge pass.
__global__ __launch_bounds__(256) void attn_kernel(const short* __restrict__ q,
                                                   const short* __restrict__ k,
                                                   const short* __restrict__ v,
                                                   float* __restrict__ opart,
                                                   float* __restrict__ mpart,
                                                   float* __restrict__ lpart) {
    __shared__ short Ksm[128][64];       // [key][d ^ swz] (linear, XOR-swizzled cols)
    __shared__ short Vsm[64][136];       // [d][key ^ swz] (transposed)
    __shared__ short Psm[4][16][136];    // per-wave P staging (one row-group at a time)
    const int tid = threadIdx.x, wid = tid >> 6, lane = tid & 63;
    const int lr = lane & 15, lg = lane >> 4;
    const int bh = blockIdx.y, b = bh >> 3, h = bh & 7;
    const int t0 = blockIdx.x * 128;
    const int split = blockIdx.z;
    const int s_begin = split * 2048, s_end = s_begin + 2048;
    const long base = (long)b * 4096 * 1536 + h * 64;

    // Q frags, pre-scaled by 0.125 * log2(e) -> exp2-domain softmax
    short8 qf[2][2];
#pragma unroll
    for (int rg = 0; rg < 2; rg++) {
        const long qoff = base + (long)(t0 + wid * 32 + rg * 16 + lr) * 1536 + lg * 8;
        short8 q0 = *(const short8*)&q[qoff];
        short8 q1 = *(const short8*)&q[qoff + 32];
#pragma unroll
        for (int i = 0; i < 8; i++) {
            qf[rg][0][i] = f2bf(bf2f(q0[i]) * 0.18033688f);
            qf[rg][1][i] = f2bf(bf2f(q1[i]) * 0.18033688f);
        }
    }

    f32x4 o[2][4];
    float mrow[8], lrow[8];
#pragma unroll
    for (int rg = 0; rg < 2; rg++)
#pragma unroll
        for (int n = 0; n < 4; n++)
#pragma unroll
            for (int j = 0; j < 4; j++) o[rg][n][j] = 0.f;
#pragma unroll
    for (int j = 0; j < 8; j++) { mrow[j] = -1e30f; lrow[j] = 0.f; }

    const int skey = tid >> 3, sd = (tid & 7) * 8, sm = tid & 7;
    short8 kreg[4], vreg[4];
#pragma unroll
    for (int p = 0; p < 4; p++) {
        long off = base + (long)(s_begin + p * 32 + skey) * 1536 + sd;
        kreg[p] = *(const short8*)&k[off];
        vreg[p] = *(const short8*)&v[off];
    }

    for (int s0 = s_begin; s0 < s_end; s0 += 128) {
        __syncthreads();   // prior tile's LDS reads done; prefetch regs landed
        // stage regs -> LDS (K linear+XOR swizzle; V transposed + XOR swizzle)
#pragma unroll
        for (int p = 0; p < 4; p++) {
            int key = p * 32 + skey;
            *(short8*)&Ksm[key][sd ^ ((key & 7) << 3)] = kreg[p];
            int kc = key ^ (sm << 3);
#pragma unroll
            for (int i = 0; i < 8; i++) Vsm[sd + i][kc] = vreg[p][i];
        }
        __syncthreads();
        if (s0 + 128 < s_end) {
#pragma unroll
            for (int p = 0; p < 4; p++) {
                long off = base + (long)(s0 + 128 + p * 32 + skey) * 1536 + sd;
                kreg[p] = *(const short8*)&k[off];
                vreg[p] = *(const short8*)&v[off];
            }
        }

        // QK^T, both row-groups sharing each K fragment (halved K LDS reads)
        f32x4 s[2][8];
#pragma unroll
        for (int rg = 0; rg < 2; rg++)
#pragma unroll
            for (int c = 0; c < 8; c++) { s[rg][c][0] = 0.f; s[rg][c][1] = 0.f; s[rg][c][2] = 0.f; s[rg][c][3] = 0.f; }
        __builtin_amdgcn_s_setprio(1);
        const int ksw = (lr & 7) << 3;
#pragma unroll
        for (int c = 0; c < 8; c++) {
            const int krow = c * 16 + lr;
            short8 kf0 = *(const short8*)&Ksm[krow][(lg * 8) ^ ksw];
            short8 kf1 = *(const short8*)&Ksm[krow][(32 + lg * 8) ^ ksw];
            s[0][c] = __builtin_amdgcn_mfma_f32_16x16x32_bf16(qf[0][0], kf0, s[0][c], 0, 0, 0);
            s[0][c] = __builtin_amdgcn_mfma_f32_16x16x32_bf16(qf[0][1], kf1, s[0][c], 0, 0, 0);
            s[1][c] = __builtin_amdgcn_mfma_f32_16x16x32_bf16(qf[1][0], kf0, s[1][c], 0, 0, 0);
            s[1][c] = __builtin_amdgcn_mfma_f32_16x16x32_bf16(qf[1][1], kf1, s[1][c], 0, 0, 0);
        }
        __builtin_amdgcn_s_setprio(0);

#pragma unroll
        for (int rg = 0; rg < 2; rg++) {
            // online softmax (exp2 domain, defer-max THR=8)
#pragma unroll
            for (int j = 0; j < 4; j++) {
                const int r8 = rg * 4 + j;
                float m01 = fmaxf(s[rg][0][j], s[rg][1][j]), m23 = fmaxf(s[rg][2][j], s[rg][3][j]);
                float m45 = fmaxf(s[rg][4][j], s[rg][5][j]), m67 = fmaxf(s[rg][6][j], s[rg][7][j]);
                float mx = fmaxf(fmaxf(m01, m23), fmaxf(m45, m67));
                mx = fmaxf(mx, __shfl_xor(mx, 1));
                mx = fmaxf(mx, __shfl_xor(mx, 2));
                mx = fmaxf(mx, __shfl_xor(mx, 4));
                mx = fmaxf(mx, __shfl_xor(mx, 8));
                float mn = mrow[r8];
                if (!__all(mx <= mn + 8.0f)) {
                    mn = fmaxf(mrow[r8], mx);
                    float alpha = exp2_fast(mrow[r8] - mn);
                    mrow[r8] = mn;
                    lrow[r8] *= alpha;
#pragma unroll
                    for (int n = 0; n < 4; n++) o[rg][n][j] *= alpha;
                }
                float rs = 0.f;
#pragma unroll
                for (int c = 0; c < 8; c++) {
                    float e = exp2_fast(s[rg][c][j] - mn);
                    s[rg][c][j] = e;
                    rs += e;
                }
                rs += __shfl_xor(rs, 1);
                rs += __shfl_xor(rs, 2);
                rs += __shfl_xor(rs, 4);
                rs += __shfl_xor(rs, 8);
                lrow[r8] += rs;
            }

            // stage P (packed bf16), wave-private slice
#pragma unroll
            for (int j = 0; j < 4; j++) {
                short* prow = &Psm[wid][lg * 4 + j][lr];
#pragma unroll
                for (int c = 0; c < 8; c += 2) {
                    unsigned pk = cvt_pk_bf16(s[rg][c][j], s[rg][c + 1][j]);
                    prow[c * 16]      = (short)(pk & 0xffff);
                    prow[c * 16 + 16] = (short)(pk >> 16);
                }
            }
            short8 pa[4];
#pragma unroll
            for (int kk = 0; kk < 4; kk++) pa[kk] = *(const short8*)&Psm[wid][lr][kk * 32 + lg * 8];

            __builtin_amdgcn_s_setprio(1);
#pragma unroll
            for (int n = 0; n < 4; n++) {
                const int vrow = n * 16 + lr;
                const int vsw = ((vrow >> 3) & 7) << 3;
#pragma unroll
                for (int kk = 0; kk < 4; kk++) {
                    short8 vf = *(const short8*)&Vsm[vrow][(kk * 32 + lg * 8) ^ vsw];
                    o[rg][n] = __builtin_amdgcn_mfma_f32_16x16x32_bf16(pa[kk], vf, o[rg][n], 0, 0, 0);
                }
            }
            __builtin_amdgcn_s_setprio(0);
        }
    }

    // write partials (un-normalized O, fp32) + m/l
    const long rowbase = (long)b * 4096 + t0 + wid * 32;
    const long ob = ((long)split * 8192 + rowbase) * 512 + h * 64;
#pragma unroll
    for (int rg = 0; rg < 2; rg++)
#pragma unroll
        for (int j = 0; j < 4; j++)
#pragma unroll
            for (int n = 0; n < 4; n++)
                opart[ob + (long)(rg * 16 + lg * 4 + j) * 512 + n * 16 + lr] = o[rg][n][j];
    if (lr == 0) {
#pragma unroll
        for (int rg = 0; rg < 2; rg++)
#pragma unroll
            for (int j = 0; j < 4; j++) {
                long idx = ((long)split * 8192 + rowbase + rg * 16 + lg * 4 + j) * 8 + h;
                mpart[idx] = mrow[rg * 4 + j];
                lpart[idx] = lrow[rg * 4 + j];
            }
    }
}

// ---------------- Split-KV merge: combine 2 partials -> bf16 ctx ----------------
__global__ __launch_bounds__(256) void attn_merge(const float* __restrict__ op,
                                                  const float* __restrict__ mp,
                                                  const float* __restrict__ lp,
                                                  short* __restrict__ ctx) {
    const int wid = threadIdx.x >> 6, lane = threadIdx.x & 63;
    const long row = (long)blockIdx.x * 4 + wid;
    const int c0 = lane * 8, h = c0 >> 6;
    float m0 = mp[row * 8 + h], m1 = mp[(8192 + row) * 8 + h];
    float l0 = lp[row * 8 + h], l1 = lp[(8192 + row) * 8 + h];
    float M = fmaxf(m0, m1);
    float w0 = exp2_fast(m0 - M), w1 = exp2_fast(m1 - M);
    float inv = 1.0f / (w0 * l0 + w1 * l1);
    w0 *= inv; w1 *= inv;
    f32x4 a0 = *(const f32x4*)&op[row * 512 + c0];
    f32x4 a1 = *(const f32x4*)&op[row * 512 + c0 + 4];
    f32x4 b0 = *(const f32x4*)&op[(8192 + row) * 512 + c0];
    f32x4 b1 = *(const f32x4*)&op[(8192 + row) * 512 + c0 + 4];
    short8 o;
#pragma unroll
    for (int i = 0; i < 4; i++) {
        o[i]     = f2bf(w0 * a0[i] + w1 * b0[i]);
        o[4 + i] = f2bf(w0 * a1[i] + w1 * b1[i]);
    }
    *(short8*)&ctx[row * 512 + c0] = o;
}

// ---------------- Orchestration ----------------
extern "C" void kernel_launch(void* const* d_in, const int* in_sizes, int n_in,
                              void* d_out, int out_size, void* d_ws, size_t ws_size,
                              hipStream_t stream) {
    (void)in_sizes; (void)n_in; (void)out_size; (void)ws_size;
    const float* inputs = (const float*)d_in[0];
    const float* ln1_s  = (const float*)d_in[1];
    const float* ln1_o  = (const float*)d_in[2];
    const float* wq     = (const float*)d_in[3];
    const float* bq     = (const float*)d_in[4];
    const float* wk     = (const float*)d_in[5];
    const float* bk     = (const float*)d_in[6];
    const float* wv     = (const float*)d_in[7];
    const float* bv     = (const float*)d_in[8];
    const float* wo     = (const float*)d_in[9];
    const float* bo     = (const float*)d_in[10];
    const float* ln2_s  = (const float*)d_in[11];
    const float* ln2_o  = (const float*)d_in[12];
    const float* w1     = (const float*)d_in[13];
    const float* b1     = (const float*)d_in[14];
    const float* w2     = (const float*)d_in[15];
    const float* b2     = (const float*)d_in[16];
    float* out = (float*)d_out;

    char* p = (char*)d_ws;
    auto alloc = [&](size_t bytes) { void* r = (void*)p; p += (bytes + 255) & ~(size_t)255; return r; };
    short* x1    = (short*)alloc((size_t)8192 * 512 * 2);
    short* qkvb  = (short*)alloc((size_t)8192 * 1536 * 2);
    short* ctxb  = (short*)alloc((size_t)8192 * 512 * 2);
    short* yb    = (short*)alloc((size_t)8192 * 512 * 2);
    short* hb    = (short*)alloc((size_t)8192 * 2048 * 2);
    short* wqkvt = (short*)alloc((size_t)1536 * 512 * 2);
    short* wot   = (short*)alloc((size_t)512 * 512 * 2);
    short* w1t   = (short*)alloc((size_t)2048 * 512 * 2);
    short* w2t   = (short*)alloc((size_t)512 * 2048 * 2);
    float* bqkv  = (float*)alloc((size_t)1536 * 4);
    float* opart = (float*)alloc((size_t)2 * 8192 * 512 * 4);
    float* mpart = (float*)alloc((size_t)2 * 8192 * 8 * 4);
    float* lpart = (float*)alloc((size_t)2 * 8192 * 8 * 4);

    dim3 blk(256);
    prep_kernel<<<769, blk, 0, stream>>>(wq, wk, wv, wo, w1, w2, bq, bk, bv,
                                         wqkvt, wot, w1t, w2t, bqkv);
    ln_kernel<<<2048, blk, 0, stream>>>(inputs, ln1_s, ln1_o, x1);
    // fused QKV GEMM
    gemm_bt<false, true, false><<<dim3(64, 12), blk, 0, stream>>>(x1, wqkvt, bqkv, nullptr, qkvb, 8192, 1536, 512);
    // attention: split-KV partials + merge
    attn_kernel<<<dim3(32, 16, 2), blk, 0, stream>>>(qkvb, qkvb + 512, qkvb + 1024, opart, mpart, lpart);
    attn_merge<<<2048, blk, 0, stream>>>(opart, mpart, lpart, ctxb);
    // out-proj + residual -> x (fp32, in d_out)
    gemm_bt<false, false, true><<<dim3(64, 4), blk, 0, stream>>>(ctxb, wot, bo, inputs, out, 8192, 512, 512);
    ln_kernel<<<2048, blk, 0, stream>>>(out, ln2_s, ln2_o, yb);
    // FFN1 + GELU
    gemm_bt<true, true, false><<<dim3(64, 16), blk, 0, stream>>>(yb, w1t, b1, nullptr, hb, 8192, 2048, 512);
    // FFN2 + residual -> out
    gemm_bt<false, false, true><<<dim3(64, 4), blk, 0, stream>>>(hb, w2t, b2, out, out, 8192, 512, 2048);
}

// Round 6
// 407.371 us; speedup vs baseline: 1.2418x; 1.2418x over previous
//
#include <hip/hip_runtime.h>
#include <hip/hip_bf16.h>

typedef __attribute__((ext_vector_type(4))) float f32x4;
typedef __attribute__((ext_vector_type(8))) short short8;

#define DEV __device__ __forceinline__

DEV short f2bf(float f) {
    union { float f; unsigned u; } a; a.f = f;
    unsigned r = a.u + 0x7fffu + ((a.u >> 16) & 1u);
    return (short)(r >> 16);
}

DEV float bf2f(short s) {
    union { unsigned u; float f; } a;
    a.u = ((unsigned)(unsigned short)s) << 16;
    return a.f;
}

// packed f32x2 -> bf16x2 (low = a, high = b), RTNE in HW
DEV unsigned cvt_pk_bf16(float a, float b) {
    unsigned r;
    asm("v_cvt_pk_bf16_f32 %0, %1, %2" : "=v"(r) : "v"(a), "v"(b));
    return r;
}

DEV float exp2_fast(float x) { return __builtin_amdgcn_exp2f(x); }

// async 16B global -> LDS (linear dest, per-lane source)
DEV void gload16(const short* g, short* l) {
    __builtin_amdgcn_global_load_lds(
        (__attribute__((address_space(1))) void*)g,
        (__attribute__((address_space(3))) void*)l, 16, 0, 0);
}

DEV float gelu_f(float x) {
    float u = 0.7978845608028654f * (x + 0.044715f * x * x * x);
    float e = __expf(2.0f * u);
    float t = 1.0f - 2.0f / (e + 1.0f);   // tanh(u)
    return 0.5f * x * (1.0f + t);
}

// ---------------- LayerNorm: fp32 in -> bf16 out, D=512, wave per row ----------------
__global__ __launch_bounds__(256) void ln_kernel(const float* __restrict__ x,
                                                 const float* __restrict__ scale,
                                                 const float* __restrict__ offset,
                                                 short* __restrict__ out) {
    const int wid = threadIdx.x >> 6, lane = threadIdx.x & 63;
    const long row = (long)blockIdx.x * 4 + wid;
    const float* xr = x + row * 512;
    f32x4 v0 = *(const f32x4*)&xr[lane * 8];
    f32x4 v1 = *(const f32x4*)&xr[lane * 8 + 4];
    float s = 0.f, sq = 0.f;
#pragma unroll
    for (int i = 0; i < 4; i++) {
        s += v0[i] + v1[i];
        sq += v0[i] * v0[i] + v1[i] * v1[i];
    }
#pragma unroll
    for (int m = 1; m < 64; m <<= 1) { s += __shfl_xor(s, m); sq += __shfl_xor(sq, m); }
    float mean = s * (1.0f / 512.0f);
    float var = sq * (1.0f / 512.0f) - mean * mean;
    float inv = rsqrtf(var + 1e-5f);
    f32x4 sc0 = *(const f32x4*)&scale[lane * 8];
    f32x4 sc1 = *(const f32x4*)&scale[lane * 8 + 4];
    f32x4 of0 = *(const f32x4*)&offset[lane * 8];
    f32x4 of1 = *(const f32x4*)&offset[lane * 8 + 4];
    short8 o;
#pragma unroll
    for (int i = 0; i < 4; i++) {
        o[i]     = f2bf((v0[i] - mean) * inv * sc0[i] + of0[i]);
        o[4 + i] = f2bf((v1[i] - mean) * inv * sc1[i] + of1[i]);
    }
    *(short8*)&out[row * 512 + lane * 8] = o;
}

// ---------------- Fused weight prep: 6 transposes + bias concat in ONE launch ----------------
__global__ __launch_bounds__(256) void prep_kernel(const float* __restrict__ wq,
                                                   const float* __restrict__ wk,
                                                   const float* __restrict__ wv,
                                                   const float* __restrict__ wo,
                                                   const float* __restrict__ w1,
                                                   const float* __restrict__ w2,
                                                   const float* __restrict__ bq,
                                                   const float* __restrict__ bk,
                                                   const float* __restrict__ bv,
                                                   short* __restrict__ wqkvt,
                                                   short* __restrict__ wot,
                                                   short* __restrict__ w1t,
                                                   short* __restrict__ w2t,
                                                   float* __restrict__ bqkv) {
    const int bid = blockIdx.x;
    if (bid == 768) {
        for (int i = threadIdx.x; i < 512; i += 256) {
            bqkv[i] = bq[i]; bqkv[512 + i] = bk[i]; bqkv[1024 + i] = bv[i];
        }
        return;
    }
    const float* src; short* dst; int Kd, N, kt, nt;
    if (bid < 256) {
        Kd = 512; N = 512;
        const int which = bid >> 6, local = bid & 63;
        kt = local & 7; nt = local >> 3;
        if (which == 0)      { src = wq; dst = wqkvt; }
        else if (which == 1) { src = wk; dst = wqkvt + 512 * 512; }
        else if (which == 2) { src = wv; dst = wqkvt + 2 * 512 * 512; }
        else                 { src = wo; dst = wot; }
    } else if (bid < 512) {
        src = w1; dst = w1t; Kd = 512; N = 2048;
        const int local = bid - 256; kt = local & 7; nt = local >> 3;
    } else {
        src = w2; dst = w2t; Kd = 2048; N = 512;
        const int local = bid - 512; kt = local & 31; nt = local >> 5;
    }
    __shared__ float tile[64][65];
    const int k0 = kt * 64, n0 = nt * 64;
    const int tid = threadIdx.x;
#pragma unroll
    for (int ld = 0; ld < 4; ld++) {
        int li = ld * 1024 + tid * 4;
        int r = li >> 6, c = li & 63;
        f32x4 tv = *(const f32x4*)&src[(long)(k0 + r) * N + n0 + c];
        tile[r][c] = tv[0]; tile[r][c + 1] = tv[1];
        tile[r][c + 2] = tv[2]; tile[r][c + 3] = tv[3];
    }
    __syncthreads();
#pragma unroll
    for (int st = 0; st < 2; st++) {
        int li = st * 2048 + tid * 8;
        int r = li >> 6, c = li & 63;
        short8 o;
#pragma unroll
        for (int i = 0; i < 8; i++) o[i] = f2bf(tile[c + i][r]);
        *(short8*)&dst[(long)(n0 + r) * Kd + k0 + c] = o;
    }
}

// ---------------- GEMM: C[M][N] = A[M][Kd] @ Bt[N][Kd]^T + bias (+gelu)(+resid) ----------------
// BM x 128 tile (BM=128: 4 waves 2x2 of 64x64; BM=64: 4 waves 1x4 of 64x32).
// global_load_lds(16B) into linear LDS; T2 swizzle via inverse-swizzled SOURCE col
// + swizzled ds_read col.
template <int BM, bool GELU_ACT, bool OUT_BF16, bool RESID>
__global__ __launch_bounds__(256) void gemm_bt(const short* __restrict__ A,
                                               const short* __restrict__ Bt,
                                               const float* __restrict__ bias,
                                               const float* __restrict__ resid,
                                               void* __restrict__ Cout,
                                               int M, int N, int Kd) {
    constexpr int NR = (BM == 128) ? 4 : 2;
    constexpr int LA = BM / 32;          // A staging rounds
    __shared__ short Asm[BM][64];
    __shared__ short Bsm[128][64];
    const int tid = threadIdx.x;
    const int wid = tid >> 6, lane = tid & 63;
    const int lr = lane & 15, lg = lane >> 4;
    const int row0 = blockIdx.x * BM, col0 = blockIdx.y * 128;
    const int wm = (BM == 128) ? (wid >> 1) * 64 : 0;
    const int wn = (BM == 128) ? (wid & 1) * 64 : wid * 32;

    f32x4 acc[4][NR];
#pragma unroll
    for (int m = 0; m < 4; m++)
#pragma unroll
        for (int n = 0; n < NR; n++)
#pragma unroll
            for (int j = 0; j < 4; j++) acc[m][n][j] = 0.f;

    const int swr = (lr & 7) << 3;   // frag-read column swizzle

    for (int k0 = 0; k0 < Kd; k0 += 64) {
#pragma unroll
        for (int ld = 0; ld < LA; ld++) {
            int off = ld * 2048 + tid * 8;
            int r = off >> 6, c = off & 63;
            int sc = c ^ ((r & 7) << 3);
            gload16(&A[(long)(row0 + r) * Kd + k0 + sc], &Asm[0][0] + off);
        }
#pragma unroll
        for (int ld = 0; ld < 4; ld++) {
            int off = ld * 2048 + tid * 8;
            int r = off >> 6, c = off & 63;
            int sc = c ^ ((r & 7) << 3);
            gload16(&Bt[(long)(col0 + r) * Kd + k0 + sc], &Bsm[0][0] + off);
        }
        __syncthreads();   // drains vmcnt -> LDS tiles ready
#pragma unroll
        for (int kk = 0; kk < 64; kk += 32) {
            short8 af[4], bf[NR];
#pragma unroll
            for (int m = 0; m < 4; m++) af[m] = *(const short8*)&Asm[wm + m * 16 + lr][(kk + lg * 8) ^ swr];
#pragma unroll
            for (int n = 0; n < NR; n++) bf[n] = *(const short8*)&Bsm[wn + n * 16 + lr][(kk + lg * 8) ^ swr];
#pragma unroll
            for (int m = 0; m < 4; m++)
#pragma unroll
                for (int n = 0; n < NR; n++)
                    acc[m][n] = __builtin_amdgcn_mfma_f32_16x16x32_bf16(af[m], bf[n], acc[m][n], 0, 0, 0);
        }
        __syncthreads();
    }

#pragma unroll
    for (int m = 0; m < 4; m++) {
#pragma unroll
        for (int n = 0; n < NR; n++) {
#pragma unroll
            for (int j = 0; j < 4; j++) {
                int r = row0 + wm + m * 16 + lg * 4 + j;
                int c = col0 + wn + n * 16 + lr;
                float v = acc[m][n][j] + bias[c];
                if constexpr (GELU_ACT) v = gelu_f(v);
                if constexpr (RESID) v += resid[(long)r * N + c];
                if constexpr (OUT_BF16) ((short*)Cout)[(long)r * N + c] = f2bf(v);
                else                    ((float*)Cout)[(long)r * N + c] = v;
            }
        }
    }
}

// ---------------- Flash attention v5: split-KV, VGPR <= 128 ----------------
// grid (32, 16, 2): 128 q-rows x (b,h) x KV-split(2048 keys). 4 waves x 32 rows.
// Per-rg QK loop (K frags read twice) keeps live accumulators at s[8] -> no
// VGPR cliff (the round-5 s[2][8] sharing hit 140 VGPR -> 2 waves/SIMD).
__global__ __launch_bounds__(256) void attn_kernel(const short* __restrict__ q,
                                                   const short* __restrict__ k,
                                                   const short* __restrict__ v,
                                                   float* __restrict__ opart,
                                                   float* __restrict__ mpart,
                                                   float* __restrict__ lpart) {
    __shared__ short Ksm[128][64];       // [key][d ^ swz] (linear, XOR-swizzled cols)
    __shared__ short Vsm[64][136];       // [d][key ^ swz] (transposed)
    __shared__ short Psm[4][16][136];    // per-wave P staging (one row-group at a time)
    const int tid = threadIdx.x, wid = tid >> 6, lane = tid & 63;
    const int lr = lane & 15, lg = lane >> 4;
    const int bh = blockIdx.y, b = bh >> 3, h = bh & 7;
    const int t0 = blockIdx.x * 128;
    const int split = blockIdx.z;
    const int s_begin = split * 2048, s_end = s_begin + 2048;
    const long base = (long)b * 4096 * 1536 + h * 64;

    // Q frags, pre-scaled by 0.125 * log2(e) -> exp2-domain softmax
    short8 qf[2][2];
#pragma unroll
    for (int rg = 0; rg < 2; rg++) {
        const long qoff = base + (long)(t0 + wid * 32 + rg * 16 + lr) * 1536 + lg * 8;
        short8 q0 = *(const short8*)&q[qoff];
        short8 q1 = *(const short8*)&q[qoff + 32];
#pragma unroll
        for (int i = 0; i < 8; i++) {
            qf[rg][0][i] = f2bf(bf2f(q0[i]) * 0.18033688f);
            qf[rg][1][i] = f2bf(bf2f(q1[i]) * 0.18033688f);
        }
    }

    f32x4 o[2][4];
    float mrow[8], lrow[8];
#pragma unroll
    for (int rg = 0; rg < 2; rg++)
#pragma unroll
        for (int n = 0; n < 4; n++)
#pragma unroll
            for (int j = 0; j < 4; j++) o[rg][n][j] = 0.f;
#pragma unroll
    for (int j = 0; j < 8; j++) { mrow[j] = -1e30f; lrow[j] = 0.f; }

    const int skey = tid >> 3, sd = (tid & 7) * 8, sm = tid & 7;
    short8 kreg[4], vreg[4];
#pragma unroll
    for (int p = 0; p < 4; p++) {
        long off = base + (long)(s_begin + p * 32 + skey) * 1536 + sd;
        kreg[p] = *(const short8*)&k[off];
        vreg[p] = *(const short8*)&v[off];
    }

    for (int s0 = s_begin; s0 < s_end; s0 += 128) {
        __syncthreads();   // prior tile's LDS reads done; prefetch regs landed
        // stage regs -> LDS (K linear+XOR swizzle; V transposed + XOR swizzle)
#pragma unroll
        for (int p = 0; p < 4; p++) {
            int key = p * 32 + skey;
            *(short8*)&Ksm[key][sd ^ ((key & 7) << 3)] = kreg[p];
            int kc = key ^ (sm << 3);
#pragma unroll
            for (int i = 0; i < 8; i++) Vsm[sd + i][kc] = vreg[p][i];
        }
        __syncthreads();
        if (s0 + 128 < s_end) {
#pragma unroll
            for (int p = 0; p < 4; p++) {
                long off = base + (long)(s0 + 128 + p * 32 + skey) * 1536 + sd;
                kreg[p] = *(const short8*)&k[off];
                vreg[p] = *(const short8*)&v[off];
            }
        }

        const int ksw = (lr & 7) << 3;
#pragma unroll
        for (int rg = 0; rg < 2; rg++) {
            // QK^T (log2-domain scores), 8 key-chunks x K=64
            f32x4 s[8];
#pragma unroll
            for (int c = 0; c < 8; c++) { s[c][0] = 0.f; s[c][1] = 0.f; s[c][2] = 0.f; s[c][3] = 0.f; }
            __builtin_amdgcn_s_setprio(1);
#pragma unroll
            for (int c = 0; c < 8; c++) {
                const int krow = c * 16 + lr;
                short8 kf0 = *(const short8*)&Ksm[krow][(lg * 8) ^ ksw];
                short8 kf1 = *(const short8*)&Ksm[krow][(32 + lg * 8) ^ ksw];
                s[c] = __builtin_amdgcn_mfma_f32_16x16x32_bf16(qf[rg][0], kf0, s[c], 0, 0, 0);
                s[c] = __builtin_amdgcn_mfma_f32_16x16x32_bf16(qf[rg][1], kf1, s[c], 0, 0, 0);
            }
            __builtin_amdgcn_s_setprio(0);

            // online softmax (exp2 domain, defer-max THR=8 -> P <= 256, bf16-safe)
#pragma unroll
            for (int j = 0; j < 4; j++) {
                const int r8 = rg * 4 + j;
                float m01 = fmaxf(s[0][j], s[1][j]), m23 = fmaxf(s[2][j], s[3][j]);
                float m45 = fmaxf(s[4][j], s[5][j]), m67 = fmaxf(s[6][j], s[7][j]);
                float mx = fmaxf(fmaxf(m01, m23), fmaxf(m45, m67));
                mx = fmaxf(mx, __shfl_xor(mx, 1));
                mx = fmaxf(mx, __shfl_xor(mx, 2));
                mx = fmaxf(mx, __shfl_xor(mx, 4));
                mx = fmaxf(mx, __shfl_xor(mx, 8));
                float mn = mrow[r8];
                if (!__all(mx <= mn + 8.0f)) {
                    mn = fmaxf(mrow[r8], mx);
                    float alpha = exp2_fast(mrow[r8] - mn);
                    mrow[r8] = mn;
                    lrow[r8] *= alpha;
#pragma unroll
                    for (int n = 0; n < 4; n++) o[rg][n][j] *= alpha;
                }
                float rs = 0.f;
#pragma unroll
                for (int c = 0; c < 8; c++) {
                    float e = exp2_fast(s[c][j] - mn);
                    s[c][j] = e;
                    rs += e;
                }
                rs += __shfl_xor(rs, 1);
                rs += __shfl_xor(rs, 2);
                rs += __shfl_xor(rs, 4);
                rs += __shfl_xor(rs, 8);
                lrow[r8] += rs;
            }

            // stage P (packed bf16), wave-private slice
#pragma unroll
            for (int j = 0; j < 4; j++) {
                short* prow = &Psm[wid][lg * 4 + j][lr];
#pragma unroll
                for (int c = 0; c < 8; c += 2) {
                    unsigned pk = cvt_pk_bf16(s[c][j], s[c + 1][j]);
                    prow[c * 16]      = (short)(pk & 0xffff);
                    prow[c * 16 + 16] = (short)(pk >> 16);
                }
            }
            short8 pa[4];
#pragma unroll
            for (int kk = 0; kk < 4; kk++) pa[kk] = *(const short8*)&Psm[wid][lr][kk * 32 + lg * 8];

            __builtin_amdgcn_s_setprio(1);
#pragma unroll
            for (int n = 0; n < 4; n++) {
                const int vrow = n * 16 + lr;
                const int vsw = ((vrow >> 3) & 7) << 3;
#pragma unroll
                for (int kk = 0; kk < 4; kk++) {
                    short8 vf = *(const short8*)&Vsm[vrow][(kk * 32 + lg * 8) ^ vsw];
                    o[rg][n] = __builtin_amdgcn_mfma_f32_16x16x32_bf16(pa[kk], vf, o[rg][n], 0, 0, 0);
                }
            }
            __builtin_amdgcn_s_setprio(0);
        }
    }

    // write partials (un-normalized O, fp32) + m/l
    const long rowbase = (long)b * 4096 + t0 + wid * 32;
    const long ob = ((long)split * 8192 + rowbase) * 512 + h * 64;
#pragma unroll
    for (int rg = 0; rg < 2; rg++)
#pragma unroll
        for (int j = 0; j < 4; j++)
#pragma unroll
            for (int n = 0; n < 4; n++)
                opart[ob + (long)(rg * 16 + lg * 4 + j) * 512 + n * 16 + lr] = o[rg][n][j];
    if (lr == 0) {
#pragma unroll
        for (int rg = 0; rg < 2; rg++)
#pragma unroll
            for (int j = 0; j < 4; j++) {
                long idx = ((long)split * 8192 + rowbase + rg * 16 + lg * 4 + j) * 8 + h;
                mpart[idx] = mrow[rg * 4 + j];
                lpart[idx] = lrow[rg * 4 + j];
            }
    }
}

// ---------------- Split-KV merge: combine 2 partials -> bf16 ctx ----------------
__global__ __launch_bounds__(256) void attn_merge(const float* __restrict__ op,
                                                  const float* __restrict__ mp,
                                                  const float* __restrict__ lp,
                                                  short* __restrict__ ctx) {
    const int wid = threadIdx.x >> 6, lane = threadIdx.x & 63;
    const long row = (long)blockIdx.x * 4 + wid;
    const int c0 = lane * 8, h = c0 >> 6;
    float m0 = mp[row * 8 + h], m1 = mp[(8192 + row) * 8 + h];
    float l0 = lp[row * 8 + h], l1 = lp[(8192 + row) * 8 + h];
    float M = fmaxf(m0, m1);
    float w0 = exp2_fast(m0 - M), w1 = exp2_fast(m1 - M);
    float inv = 1.0f / (w0 * l0 + w1 * l1);
    w0 *= inv; w1 *= inv;
    f32x4 a0 = *(const f32x4*)&op[row * 512 + c0];
    f32x4 a1 = *(const f32x4*)&op[row * 512 + c0 + 4];
    f32x4 b0 = *(const f32x4*)&op[(8192 + row) * 512 + c0];
    f32x4 b1 = *(const f32x4*)&op[(8192 + row) * 512 + c0 + 4];
    short8 o;
#pragma unroll
    for (int i = 0; i < 4; i++) {
        o[i]     = f2bf(w0 * a0[i] + w1 * b0[i]);
        o[4 + i] = f2bf(w0 * a1[i] + w1 * b1[i]);
    }
    *(short8*)&ctx[row * 512 + c0] = o;
}

// ---------------- Orchestration ----------------
extern "C" void kernel_launch(void* const* d_in, const int* in_sizes, int n_in,
                              void* d_out, int out_size, void* d_ws, size_t ws_size,
                              hipStream_t stream) {
    (void)in_sizes; (void)n_in; (void)out_size; (void)ws_size;
    const float* inputs = (const float*)d_in[0];
    const float* ln1_s  = (const float*)d_in[1];
    const float* ln1_o  = (const float*)d_in[2];
    const float* wq     = (const float*)d_in[3];
    const float* bq     = (const float*)d_in[4];
    const float* wk     = (const float*)d_in[5];
    const float* bk     = (const float*)d_in[6];
    const float* wv     = (const float*)d_in[7];
    const float* bv     = (const float*)d_in[8];
    const float* wo     = (const float*)d_in[9];
    const float* bo     = (const float*)d_in[10];
    const float* ln2_s  = (const float*)d_in[11];
    const float* ln2_o  = (const float*)d_in[12];
    const float* w1     = (const float*)d_in[13];
    const float* b1     = (const float*)d_in[14];
    const float* w2     = (const float*)d_in[15];
    const float* b2     = (const float*)d_in[16];
    float* out = (float*)d_out;

    char* p = (char*)d_ws;
    auto alloc = [&](size_t bytes) { void* r = (void*)p; p += (bytes + 255) & ~(size_t)255; return r; };
    short* x1    = (short*)alloc((size_t)8192 * 512 * 2);
    short* qkvb  = (short*)alloc((size_t)8192 * 1536 * 2);
    short* ctxb  = (short*)alloc((size_t)8192 * 512 * 2);
    short* yb    = (short*)alloc((size_t)8192 * 512 * 2);
    short* hb    = (short*)alloc((size_t)8192 * 2048 * 2);
    short* wqkvt = (short*)alloc((size_t)1536 * 512 * 2);
    short* wot   = (short*)alloc((size_t)512 * 512 * 2);
    short* w1t   = (short*)alloc((size_t)2048 * 512 * 2);
    short* w2t   = (short*)alloc((size_t)512 * 2048 * 2);
    float* bqkv  = (float*)alloc((size_t)1536 * 4);
    float* opart = (float*)alloc((size_t)2 * 8192 * 512 * 4);
    float* mpart = (float*)alloc((size_t)2 * 8192 * 8 * 4);
    float* lpart = (float*)alloc((size_t)2 * 8192 * 8 * 4);

    dim3 blk(256);
    prep_kernel<<<769, blk, 0, stream>>>(wq, wk, wv, wo, w1, w2, bq, bk, bv,
                                         wqkvt, wot, w1t, w2t, bqkv);
    ln_kernel<<<2048, blk, 0, stream>>>(inputs, ln1_s, ln1_o, x1);
    // fused QKV GEMM (128x128 tiles, 768 blocks)
    gemm_bt<128, false, true, false><<<dim3(64, 12), blk, 0, stream>>>(x1, wqkvt, bqkv, nullptr, qkvb, 8192, 1536, 512);
    // attention: split-KV partials + merge
    attn_kernel<<<dim3(32, 16, 2), blk, 0, stream>>>(qkvb, qkvb + 512, qkvb + 1024, opart, mpart, lpart);
    attn_merge<<<2048, blk, 0, stream>>>(opart, mpart, lpart, ctxb);
    // out-proj + residual -> x (fp32, in d_out); 64x128 tiles -> 512 blocks
    gemm_bt<64, false, false, true><<<dim3(128, 4), blk, 0, stream>>>(ctxb, wot, bo, inputs, out, 8192, 512, 512);
    ln_kernel<<<2048, blk, 0, stream>>>(out, ln2_s, ln2_o, yb);
    // FFN1 + GELU (128x128 tiles, 1024 blocks)
    gemm_bt<128, true, true, false><<<dim3(64, 16), blk, 0, stream>>>(yb, w1t, b1, nullptr, hb, 8192, 2048, 512);
    // FFN2 + residual -> out; 64x128 tiles -> 512 blocks
    gemm_bt<64, false, false, true><<<dim3(128, 4), blk, 0, stream>>>(hb, w2t, b2, out, out, 8192, 512, 2048);
}

// Round 7
// 350.487 us; speedup vs baseline: 1.4433x; 1.1623x over previous
//
#include <hip/hip_runtime.h>
#include <hip/hip_bf16.h>

typedef __attribute__((ext_vector_type(4))) float f32x4;
typedef __attribute__((ext_vector_type(8))) short short8;
typedef __attribute__((ext_vector_type(2))) unsigned u32x2;

#define DEV __device__ __forceinline__

DEV short f2bf(float f) {
    union { float f; unsigned u; } a; a.f = f;
    unsigned r = a.u + 0x7fffu + ((a.u >> 16) & 1u);
    return (short)(r >> 16);
}

DEV float bf2f(short s) {
    union { unsigned u; float f; } a;
    a.u = ((unsigned)(unsigned short)s) << 16;
    return a.f;
}

// packed f32x2 -> bf16x2 (low = a, high = b), RTNE in HW
DEV unsigned cvt_pk_bf16(float a, float b) {
    unsigned r;
    asm("v_cvt_pk_bf16_f32 %0, %1, %2" : "=v"(r) : "v"(a), "v"(b));
    return r;
}

DEV float exp2_fast(float x) { return __builtin_amdgcn_exp2f(x); }

// async 16B global -> LDS (linear dest, per-lane source)
DEV void gload16(const short* g, short* l) {
    __builtin_amdgcn_global_load_lds(
        (__attribute__((address_space(1))) void*)g,
        (__attribute__((address_space(3))) void*)l, 16, 0, 0);
}

DEV float gelu_f(float x) {
    float u = 0.7978845608028654f * (x + 0.044715f * x * x * x);
    float e = __expf(2.0f * u);
    float t = 1.0f - 2.0f / (e + 1.0f);   // tanh(u)
    return 0.5f * x * (1.0f + t);
}

// ---------------- LayerNorm: fp32 in -> bf16 out, D=512, wave per row ----------------
__global__ __launch_bounds__(256) void ln_kernel(const float* __restrict__ x,
                                                 const float* __restrict__ scale,
                                                 const float* __restrict__ offset,
                                                 short* __restrict__ out) {
    const int wid = threadIdx.x >> 6, lane = threadIdx.x & 63;
    const long row = (long)blockIdx.x * 4 + wid;
    const float* xr = x + row * 512;
    f32x4 v0 = *(const f32x4*)&xr[lane * 8];
    f32x4 v1 = *(const f32x4*)&xr[lane * 8 + 4];
    float s = 0.f, sq = 0.f;
#pragma unroll
    for (int i = 0; i < 4; i++) {
        s += v0[i] + v1[i];
        sq += v0[i] * v0[i] + v1[i] * v1[i];
    }
#pragma unroll
    for (int m = 1; m < 64; m <<= 1) { s += __shfl_xor(s, m); sq += __shfl_xor(sq, m); }
    float mean = s * (1.0f / 512.0f);
    float var = sq * (1.0f / 512.0f) - mean * mean;
    float inv = rsqrtf(var + 1e-5f);
    f32x4 sc0 = *(const f32x4*)&scale[lane * 8];
    f32x4 sc1 = *(const f32x4*)&scale[lane * 8 + 4];
    f32x4 of0 = *(const f32x4*)&offset[lane * 8];
    f32x4 of1 = *(const f32x4*)&offset[lane * 8 + 4];
    short8 o;
#pragma unroll
    for (int i = 0; i < 4; i++) {
        o[i]     = f2bf((v0[i] - mean) * inv * sc0[i] + of0[i]);
        o[4 + i] = f2bf((v1[i] - mean) * inv * sc1[i] + of1[i]);
    }
    *(short8*)&out[row * 512 + lane * 8] = o;
}

// ---------------- Fused weight prep: 6 transposes + bias concat in ONE launch ----------------
__global__ __launch_bounds__(256) void prep_kernel(const float* __restrict__ wq,
                                                   const float* __restrict__ wk,
                                                   const float* __restrict__ wv,
                                                   const float* __restrict__ wo,
                                                   const float* __restrict__ w1,
                                                   const float* __restrict__ w2,
                                                   const float* __restrict__ bq,
                                                   const float* __restrict__ bk,
                                                   const float* __restrict__ bv,
                                                   short* __restrict__ wqkvt,
                                                   short* __restrict__ wot,
                                                   short* __restrict__ w1t,
                                                   short* __restrict__ w2t,
                                                   float* __restrict__ bqkv) {
    const int bid = blockIdx.x;
    if (bid == 768) {
        for (int i = threadIdx.x; i < 512; i += 256) {
            bqkv[i] = bq[i]; bqkv[512 + i] = bk[i]; bqkv[1024 + i] = bv[i];
        }
        return;
    }
    const float* src; short* dst; int Kd, N, kt, nt;
    if (bid < 256) {
        Kd = 512; N = 512;
        const int which = bid >> 6, local = bid & 63;
        kt = local & 7; nt = local >> 3;
        if (which == 0)      { src = wq; dst = wqkvt; }
        else if (which == 1) { src = wk; dst = wqkvt + 512 * 512; }
        else if (which == 2) { src = wv; dst = wqkvt + 2 * 512 * 512; }
        else                 { src = wo; dst = wot; }
    } else if (bid < 512) {
        src = w1; dst = w1t; Kd = 512; N = 2048;
        const int local = bid - 256; kt = local & 7; nt = local >> 3;
    } else {
        src = w2; dst = w2t; Kd = 2048; N = 512;
        const int local = bid - 512; kt = local & 31; nt = local >> 5;
    }
    __shared__ float tile[64][65];
    const int k0 = kt * 64, n0 = nt * 64;
    const int tid = threadIdx.x;
#pragma unroll
    for (int ld = 0; ld < 4; ld++) {
        int li = ld * 1024 + tid * 4;
        int r = li >> 6, c = li & 63;
        f32x4 tv = *(const f32x4*)&src[(long)(k0 + r) * N + n0 + c];
        tile[r][c] = tv[0]; tile[r][c + 1] = tv[1];
        tile[r][c + 2] = tv[2]; tile[r][c + 3] = tv[3];
    }
    __syncthreads();
#pragma unroll
    for (int st = 0; st < 2; st++) {
        int li = st * 2048 + tid * 8;
        int r = li >> 6, c = li & 63;
        short8 o;
#pragma unroll
        for (int i = 0; i < 8; i++) o[i] = f2bf(tile[c + i][r]);
        *(short8*)&dst[(long)(n0 + r) * Kd + k0 + c] = o;
    }
}

// ---------------- GEMM: C[M][N] = A[M][Kd] @ Bt[N][Kd]^T + bias (+gelu)(+resid) ----------------
template <int BM, bool GELU_ACT, bool OUT_BF16, bool RESID>
__global__ __launch_bounds__(256) void gemm_bt(const short* __restrict__ A,
                                               const short* __restrict__ Bt,
                                               const float* __restrict__ bias,
                                               const float* __restrict__ resid,
                                               void* __restrict__ Cout,
                                               int M, int N, int Kd) {
    constexpr int NR = (BM == 128) ? 4 : 2;
    constexpr int LA = BM / 32;          // A staging rounds
    __shared__ short Asm[BM][64];
    __shared__ short Bsm[128][64];
    const int tid = threadIdx.x;
    const int wid = tid >> 6, lane = tid & 63;
    const int lr = lane & 15, lg = lane >> 4;
    const int row0 = blockIdx.x * BM, col0 = blockIdx.y * 128;
    const int wm = (BM == 128) ? (wid >> 1) * 64 : 0;
    const int wn = (BM == 128) ? (wid & 1) * 64 : wid * 32;

    f32x4 acc[4][NR];
#pragma unroll
    for (int m = 0; m < 4; m++)
#pragma unroll
        for (int n = 0; n < NR; n++)
#pragma unroll
            for (int j = 0; j < 4; j++) acc[m][n][j] = 0.f;

    const int swr = (lr & 7) << 3;   // frag-read column swizzle

    for (int k0 = 0; k0 < Kd; k0 += 64) {
#pragma unroll
        for (int ld = 0; ld < LA; ld++) {
            int off = ld * 2048 + tid * 8;
            int r = off >> 6, c = off & 63;
            int sc = c ^ ((r & 7) << 3);
            gload16(&A[(long)(row0 + r) * Kd + k0 + sc], &Asm[0][0] + off);
        }
#pragma unroll
        for (int ld = 0; ld < 4; ld++) {
            int off = ld * 2048 + tid * 8;
            int r = off >> 6, c = off & 63;
            int sc = c ^ ((r & 7) << 3);
            gload16(&Bt[(long)(col0 + r) * Kd + k0 + sc], &Bsm[0][0] + off);
        }
        __syncthreads();   // drains vmcnt -> LDS tiles ready
#pragma unroll
        for (int kk = 0; kk < 64; kk += 32) {
            short8 af[4], bf[NR];
#pragma unroll
            for (int m = 0; m < 4; m++) af[m] = *(const short8*)&Asm[wm + m * 16 + lr][(kk + lg * 8) ^ swr];
#pragma unroll
            for (int n = 0; n < NR; n++) bf[n] = *(const short8*)&Bsm[wn + n * 16 + lr][(kk + lg * 8) ^ swr];
#pragma unroll
            for (int m = 0; m < 4; m++)
#pragma unroll
                for (int n = 0; n < NR; n++)
                    acc[m][n] = __builtin_amdgcn_mfma_f32_16x16x32_bf16(af[m], bf[n], acc[m][n], 0, 0, 0);
        }
        __syncthreads();
    }

#pragma unroll
    for (int m = 0; m < 4; m++) {
#pragma unroll
        for (int n = 0; n < NR; n++) {
#pragma unroll
            for (int j = 0; j < 4; j++) {
                int r = row0 + wm + m * 16 + lg * 4 + j;
                int c = col0 + wn + n * 16 + lr;
                float v = acc[m][n][j] + bias[c];
                if constexpr (GELU_ACT) v = gelu_f(v);
                if constexpr (RESID) v += resid[(long)r * N + c];
                if constexpr (OUT_BF16) ((short*)Cout)[(long)r * N + c] = f2bf(v);
                else                    ((float*)Cout)[(long)r * N + c] = v;
            }
        }
    }
}

// ---------------- Flash attention v6: swapped QK^T, in-register softmax ----------------
// grid (32, 16, 2). The attn kernel was measured LDS-pipe-bound (~1840 LDS-cyc/
// wave-tile); this version cuts shfl count (swapped-QK makes the row lane-local:
// 2 shfl_xor instead of 32 per rg) and packs P staging as ds_write_b64.
// Swapped mfma(kf,qf): qrow = lane&15, key = c*16 + (lane>>4)*4 + j.
__global__ __launch_bounds__(256) void attn_kernel(const short* __restrict__ q,
                                                   const short* __restrict__ k,
                                                   const short* __restrict__ v,
                                                   float* __restrict__ opart,
                                                   float* __restrict__ mpart,
                                                   float* __restrict__ lpart) {
    __shared__ short Ksm[128][64];       // [key][d ^ swz]
    __shared__ short Vsm[64][136];       // [d][key ^ swz] (transposed)
    __shared__ short Psm[4][16][136];    // per-wave P [qrow][key]
    const int tid = threadIdx.x, wid = tid >> 6, lane = tid & 63;
    const int lr = lane & 15, lg = lane >> 4;
    const int bh = blockIdx.y, b = bh >> 3, h = bh & 7;
    const int t0 = blockIdx.x * 128;
    const int split = blockIdx.z;
    const int s_begin = split * 2048, s_end = s_begin + 2048;
    const long base = (long)b * 4096 * 1536 + h * 64;

    // Q frags, pre-scaled by 0.125 * log2(e) -> exp2-domain softmax
    short8 qf[2][2];
#pragma unroll
    for (int rg = 0; rg < 2; rg++) {
        const long qoff = base + (long)(t0 + wid * 32 + rg * 16 + lr) * 1536 + lg * 8;
        short8 q0 = *(const short8*)&q[qoff];
        short8 q1 = *(const short8*)&q[qoff + 32];
#pragma unroll
        for (int i = 0; i < 8; i++) {
            qf[rg][0][i] = f2bf(bf2f(q0[i]) * 0.18033688f);
            qf[rg][1][i] = f2bf(bf2f(q1[i]) * 0.18033688f);
        }
    }

    f32x4 o[2][4];
    float mrow[2], lrow[2];   // per-lane: stats of qrow = rg*16 + lr
#pragma unroll
    for (int rg = 0; rg < 2; rg++) {
        mrow[rg] = -1e30f; lrow[rg] = 0.f;
#pragma unroll
        for (int n = 0; n < 4; n++)
#pragma unroll
            for (int j = 0; j < 4; j++) o[rg][n][j] = 0.f;
    }

    const int skey = tid >> 3, sd = (tid & 7) * 8, sm = tid & 7;
    short8 kreg[4], vreg[4];
#pragma unroll
    for (int p = 0; p < 4; p++) {
        long off = base + (long)(s_begin + p * 32 + skey) * 1536 + sd;
        kreg[p] = *(const short8*)&k[off];
        vreg[p] = *(const short8*)&v[off];
    }

    for (int s0 = s_begin; s0 < s_end; s0 += 128) {
        __syncthreads();   // prior tile's LDS reads done; prefetch regs landed
#pragma unroll
        for (int p = 0; p < 4; p++) {
            int key = p * 32 + skey;
            *(short8*)&Ksm[key][sd ^ ((key & 7) << 3)] = kreg[p];
            int kc = key ^ (sm << 3);
#pragma unroll
            for (int i = 0; i < 8; i++) Vsm[sd + i][kc] = vreg[p][i];
        }
        __syncthreads();
        if (s0 + 128 < s_end) {
#pragma unroll
            for (int p = 0; p < 4; p++) {
                long off = base + (long)(s0 + 128 + p * 32 + skey) * 1536 + sd;
                kreg[p] = *(const short8*)&k[off];
                vreg[p] = *(const short8*)&v[off];
            }
        }

        const int ksw = (lr & 7) << 3;
#pragma unroll
        for (int rg = 0; rg < 2; rg++) {
            // QK^T swapped: s[c] rows=keys, cols=qrows
            f32x4 s[8];
#pragma unroll
            for (int c = 0; c < 8; c++) { s[c][0] = 0.f; s[c][1] = 0.f; s[c][2] = 0.f; s[c][3] = 0.f; }
            __builtin_amdgcn_s_setprio(1);
#pragma unroll
            for (int c = 0; c < 8; c++) {
                const int krow = c * 16 + lr;
                short8 kf0 = *(const short8*)&Ksm[krow][(lg * 8) ^ ksw];
                short8 kf1 = *(const short8*)&Ksm[krow][(32 + lg * 8) ^ ksw];
                s[c] = __builtin_amdgcn_mfma_f32_16x16x32_bf16(kf0, qf[rg][0], s[c], 0, 0, 0);
                s[c] = __builtin_amdgcn_mfma_f32_16x16x32_bf16(kf1, qf[rg][1], s[c], 0, 0, 0);
            }
            __builtin_amdgcn_s_setprio(0);

            // in-register online softmax for qrow = rg*16+lr (32 keys/lane)
            f32x4 m4 = s[0];
#pragma unroll
            for (int c = 1; c < 8; c++)
#pragma unroll
                for (int j = 0; j < 4; j++) m4[j] = fmaxf(m4[j], s[c][j]);
            float mx = fmaxf(fmaxf(m4[0], m4[1]), fmaxf(m4[2], m4[3]));
            mx = fmaxf(mx, __shfl_xor(mx, 16));
            mx = fmaxf(mx, __shfl_xor(mx, 32));
            float mn = mrow[rg];
            if (!__all(mx <= mn + 8.0f)) {
                mn = fmaxf(mrow[rg], mx);
                float alpha = exp2_fast(mrow[rg] - mn);
                mrow[rg] = mn;
                lrow[rg] *= alpha;
                // o rows live at qrow = lg*4+j -> pull alpha from lane lr==row
#pragma unroll
                for (int j = 0; j < 4; j++) {
                    float aj = __shfl(alpha, lg * 4 + j);
#pragma unroll
                    for (int n = 0; n < 4; n++) o[rg][n][j] *= aj;
                }
            }
            f32x4 sum4 = {0.f, 0.f, 0.f, 0.f};
#pragma unroll
            for (int c = 0; c < 8; c++)
#pragma unroll
                for (int j = 0; j < 4; j++) {
                    float e = exp2_fast(s[c][j] - mn);
                    s[c][j] = e;
                    sum4[j] += e;
                }
            float rs = (sum4[0] + sum4[1]) + (sum4[2] + sum4[3]);
            rs += __shfl_xor(rs, 16);
            rs += __shfl_xor(rs, 32);
            lrow[rg] += rs;

            // stage P: adjacent keys pack -> ds_write_b64 (8 per rg, 4-deep = min)
#pragma unroll
            for (int c = 0; c < 8; c++) {
                u32x2 w;
                w[0] = cvt_pk_bf16(s[c][0], s[c][1]);
                w[1] = cvt_pk_bf16(s[c][2], s[c][3]);
                *(u32x2*)&Psm[wid][lr][c * 16 + lg * 4] = w;
            }
            short8 pa[4];
#pragma unroll
            for (int kk = 0; kk < 4; kk++) pa[kk] = *(const short8*)&Psm[wid][lr][kk * 32 + lg * 8];

            __builtin_amdgcn_s_setprio(1);
#pragma unroll
            for (int n = 0; n < 4; n++) {
                const int vrow = n * 16 + lr;
                const int vsw = ((vrow >> 3) & 7) << 3;
#pragma unroll
                for (int kk = 0; kk < 4; kk++) {
                    short8 vf = *(const short8*)&Vsm[vrow][(kk * 32 + lg * 8) ^ vsw];
                    o[rg][n] = __builtin_amdgcn_mfma_f32_16x16x32_bf16(pa[kk], vf, o[rg][n], 0, 0, 0);
                }
            }
            __builtin_amdgcn_s_setprio(0);
        }
    }

    // write partials (un-normalized O, fp32; standard layout) + m/l (swapped layout)
    const long rowbase = (long)b * 4096 + t0 + wid * 32;
    const long ob = ((long)split * 8192 + rowbase) * 512 + h * 64;
#pragma unroll
    for (int rg = 0; rg < 2; rg++)
#pragma unroll
        for (int j = 0; j < 4; j++)
#pragma unroll
            for (int n = 0; n < 4; n++)
                opart[ob + (long)(rg * 16 + lg * 4 + j) * 512 + n * 16 + lr] = o[rg][n][j];
    if (lane < 16) {   // lg==0 lanes hold rows rg*16+lr
#pragma unroll
        for (int rg = 0; rg < 2; rg++) {
            long idx = ((long)split * 8192 + rowbase + rg * 16 + lr) * 8 + h;
            mpart[idx] = mrow[rg];
            lpart[idx] = lrow[rg];
        }
    }
}

// ---------------- Split-KV merge: combine 2 partials -> bf16 ctx ----------------
__global__ __launch_bounds__(256) void attn_merge(const float* __restrict__ op,
                                                  const float* __restrict__ mp,
                                                  const float* __restrict__ lp,
                                                  short* __restrict__ ctx) {
    const int wid = threadIdx.x >> 6, lane = threadIdx.x & 63;
    const long row = (long)blockIdx.x * 4 + wid;
    const int c0 = lane * 8, h = c0 >> 6;
    float m0 = mp[row * 8 + h], m1 = mp[(8192 + row) * 8 + h];
    float l0 = lp[row * 8 + h], l1 = lp[(8192 + row) * 8 + h];
    float M = fmaxf(m0, m1);
    float w0 = exp2_fast(m0 - M), w1 = exp2_fast(m1 - M);
    float inv = 1.0f / (w0 * l0 + w1 * l1);
    w0 *= inv; w1 *= inv;
    f32x4 a0 = *(const f32x4*)&op[row * 512 + c0];
    f32x4 a1 = *(const f32x4*)&op[row * 512 + c0 + 4];
    f32x4 b0 = *(const f32x4*)&op[(8192 + row) * 512 + c0];
    f32x4 b1 = *(const f32x4*)&op[(8192 + row) * 512 + c0 + 4];
    short8 o;
#pragma unroll
    for (int i = 0; i < 4; i++) {
        o[i]     = f2bf(w0 * a0[i] + w1 * b0[i]);
        o[4 + i] = f2bf(w0 * a1[i] + w1 * b1[i]);
    }
    *(short8*)&ctx[row * 512 + c0] = o;
}

// ---------------- Orchestration ----------------
extern "C" void kernel_launch(void* const* d_in, const int* in_sizes, int n_in,
                              void* d_out, int out_size, void* d_ws, size_t ws_size,
                              hipStream_t stream) {
    (void)in_sizes; (void)n_in; (void)out_size; (void)ws_size;
    const float* inputs = (const float*)d_in[0];
    const float* ln1_s  = (const float*)d_in[1];
    const float* ln1_o  = (const float*)d_in[2];
    const float* wq     = (const float*)d_in[3];
    const float* bq     = (const float*)d_in[4];
    const float* wk     = (const float*)d_in[5];
    const float* bk     = (const float*)d_in[6];
    const float* wv     = (const float*)d_in[7];
    const float* bv     = (const float*)d_in[8];
    const float* wo     = (const float*)d_in[9];
    const float* bo     = (const float*)d_in[10];
    const float* ln2_s  = (const float*)d_in[11];
    const float* ln2_o  = (const float*)d_in[12];
    const float* w1     = (const float*)d_in[13];
    const float* b1     = (const float*)d_in[14];
    const float* w2     = (const float*)d_in[15];
    const float* b2     = (const float*)d_in[16];
    float* out = (float*)d_out;

    char* p = (char*)d_ws;
    auto alloc = [&](size_t bytes) { void* r = (void*)p; p += (bytes + 255) & ~(size_t)255; return r; };
    short* x1    = (short*)alloc((size_t)8192 * 512 * 2);
    short* qkvb  = (short*)alloc((size_t)8192 * 1536 * 2);
    short* ctxb  = (short*)alloc((size_t)8192 * 512 * 2);
    short* yb    = (short*)alloc((size_t)8192 * 512 * 2);
    short* hb    = (short*)alloc((size_t)8192 * 2048 * 2);
    short* wqkvt = (short*)alloc((size_t)1536 * 512 * 2);
    short* wot   = (short*)alloc((size_t)512 * 512 * 2);
    short* w1t   = (short*)alloc((size_t)2048 * 512 * 2);
    short* w2t   = (short*)alloc((size_t)512 * 2048 * 2);
    float* bqkv  = (float*)alloc((size_t)1536 * 4);
    float* opart = (float*)alloc((size_t)2 * 8192 * 512 * 4);
    float* mpart = (float*)alloc((size_t)2 * 8192 * 8 * 4);
    float* lpart = (float*)alloc((size_t)2 * 8192 * 8 * 4);

    dim3 blk(256);
    prep_kernel<<<769, blk, 0, stream>>>(wq, wk, wv, wo, w1, w2, bq, bk, bv,
                                         wqkvt, wot, w1t, w2t, bqkv);
    ln_kernel<<<2048, blk, 0, stream>>>(inputs, ln1_s, ln1_o, x1);
    // fused QKV GEMM (128x128 tiles, 768 blocks)
    gemm_bt<128, false, true, false><<<dim3(64, 12), blk, 0, stream>>>(x1, wqkvt, bqkv, nullptr, qkvb, 8192, 1536, 512);
    // attention: split-KV partials + merge
    attn_kernel<<<dim3(32, 16, 2), blk, 0, stream>>>(qkvb, qkvb + 512, qkvb + 1024, opart, mpart, lpart);
    attn_merge<<<2048, blk, 0, stream>>>(opart, mpart, lpart, ctxb);
    // out-proj + residual -> x (fp32, in d_out); 64x128 tiles -> 512 blocks
    gemm_bt<64, false, false, true><<<dim3(128, 4), blk, 0, stream>>>(ctxb, wot, bo, inputs, out, 8192, 512, 512);
    ln_kernel<<<2048, blk, 0, stream>>>(out, ln2_s, ln2_o, yb);
    // FFN1 + GELU (128x128 tiles, 1024 blocks)
    gemm_bt<128, true, true, false><<<dim3(64, 16), blk, 0, stream>>>(yb, w1t, b1, nullptr, hb, 8192, 2048, 512);
    // FFN2 + residual -> out; 64x128 tiles -> 512 blocks
    gemm_bt<64, false, false, true><<<dim3(128, 4), blk, 0, stream>>>(hb, w2t, b2, out, out, 8192, 512, 2048);
}

// Round 9
// 332.834 us; speedup vs baseline: 1.5198x; 1.0530x over previous
//
#include <hip/hip_runtime.h>
#include <hip/hip_bf16.h>

typedef __attribute__((ext_vector_type(4))) float f32x4;
typedef __attribute__((ext_vector_type(16))) float f32x16;
typedef __attribute__((ext_vector_type(8))) short short8;

#define DEV __device__ __forceinline__

DEV short f2bf(float f) {
    union { float f; unsigned u; } a; a.f = f;
    unsigned r = a.u + 0x7fffu + ((a.u >> 16) & 1u);
    return (short)(r >> 16);
}

DEV float bf2f(short s) {
    union { unsigned u; float f; } a;
    a.u = ((unsigned)(unsigned short)s) << 16;
    return a.f;
}

// packed f32x2 -> bf16x2 (low = a, high = b), RTNE in HW
DEV unsigned cvt_pk_bf16(float a, float b) {
    unsigned r;
    asm("v_cvt_pk_bf16_f32 %0, %1, %2" : "=v"(r) : "v"(a), "v"(b));
    return r;
}

// v_permlane32_swap_b32 a, b: a'[32:63] = b[0:31], b'[0:31] = a[32:63].
// ONLY safe when a and b are guaranteed-distinct values (else regalloc may
// coalesce the two "+v" operands into one register -> self-swap bug).
DEV void permlane32_swap(unsigned& a, unsigned& b) {
    asm("v_permlane32_swap_b32 %0, %1" : "+v"(a), "+v"(b));
}

DEV float exp2_fast(float x) { return __builtin_amdgcn_exp2f(x); }

// async 16B global -> LDS (linear dest, per-lane source)
DEV void gload16(const short* g, short* l) {
    __builtin_amdgcn_global_load_lds(
        (__attribute__((address_space(1))) void*)g,
        (__attribute__((address_space(3))) void*)l, 16, 0, 0);
}

DEV float gelu_f(float x) {
    float u = 0.7978845608028654f * (x + 0.044715f * x * x * x);
    float e = __expf(2.0f * u);
    float t = 1.0f - 2.0f / (e + 1.0f);   // tanh(u)
    return 0.5f * x * (1.0f + t);
}

// ---------------- LayerNorm: fp32 in -> bf16 out, D=512, wave per row ----------------
__global__ __launch_bounds__(256) void ln_kernel(const float* __restrict__ x,
                                                 const float* __restrict__ scale,
                                                 const float* __restrict__ offset,
                                                 short* __restrict__ out) {
    const int wid = threadIdx.x >> 6, lane = threadIdx.x & 63;
    const long row = (long)blockIdx.x * 4 + wid;
    const float* xr = x + row * 512;
    f32x4 v0 = *(const f32x4*)&xr[lane * 8];
    f32x4 v1 = *(const f32x4*)&xr[lane * 8 + 4];
    float s = 0.f, sq = 0.f;
#pragma unroll
    for (int i = 0; i < 4; i++) {
        s += v0[i] + v1[i];
        sq += v0[i] * v0[i] + v1[i] * v1[i];
    }
#pragma unroll
    for (int m = 1; m < 64; m <<= 1) { s += __shfl_xor(s, m); sq += __shfl_xor(sq, m); }
    float mean = s * (1.0f / 512.0f);
    float var = sq * (1.0f / 512.0f) - mean * mean;
    float inv = rsqrtf(var + 1e-5f);
    f32x4 sc0 = *(const f32x4*)&scale[lane * 8];
    f32x4 sc1 = *(const f32x4*)&scale[lane * 8 + 4];
    f32x4 of0 = *(const f32x4*)&offset[lane * 8];
    f32x4 of1 = *(const f32x4*)&offset[lane * 8 + 4];
    short8 o;
#pragma unroll
    for (int i = 0; i < 4; i++) {
        o[i]     = f2bf((v0[i] - mean) * inv * sc0[i] + of0[i]);
        o[4 + i] = f2bf((v1[i] - mean) * inv * sc1[i] + of1[i]);
    }
    *(short8*)&out[row * 512 + lane * 8] = o;
}

// ---------------- Fused weight prep: 6 transposes + bias concat in ONE launch ----------------
__global__ __launch_bounds__(256) void prep_kernel(const float* __restrict__ wq,
                                                   const float* __restrict__ wk,
                                                   const float* __restrict__ wv,
                                                   const float* __restrict__ wo,
                                                   const float* __restrict__ w1,
                                                   const float* __restrict__ w2,
                                                   const float* __restrict__ bq,
                                                   const float* __restrict__ bk,
                                                   const float* __restrict__ bv,
                                                   short* __restrict__ wqkvt,
                                                   short* __restrict__ wot,
                                                   short* __restrict__ w1t,
                                                   short* __restrict__ w2t,
                                                   float* __restrict__ bqkv) {
    const int bid = blockIdx.x;
    if (bid == 768) {
        for (int i = threadIdx.x; i < 512; i += 256) {
            bqkv[i] = bq[i]; bqkv[512 + i] = bk[i]; bqkv[1024 + i] = bv[i];
        }
        return;
    }
    const float* src; short* dst; int Kd, N, kt, nt;
    if (bid < 256) {
        Kd = 512; N = 512;
        const int which = bid >> 6, local = bid & 63;
        kt = local & 7; nt = local >> 3;
        if (which == 0)      { src = wq; dst = wqkvt; }
        else if (which == 1) { src = wk; dst = wqkvt + 512 * 512; }
        else if (which == 2) { src = wv; dst = wqkvt + 2 * 512 * 512; }
        else                 { src = wo; dst = wot; }
    } else if (bid < 512) {
        src = w1; dst = w1t; Kd = 512; N = 2048;
        const int local = bid - 256; kt = local & 7; nt = local >> 3;
    } else {
        src = w2; dst = w2t; Kd = 2048; N = 512;
        const int local = bid - 512; kt = local & 31; nt = local >> 5;
    }
    __shared__ float tile[64][65];
    const int k0 = kt * 64, n0 = nt * 64;
    const int tid = threadIdx.x;
#pragma unroll
    for (int ld = 0; ld < 4; ld++) {
        int li = ld * 1024 + tid * 4;
        int r = li >> 6, c = li & 63;
        f32x4 tv = *(const f32x4*)&src[(long)(k0 + r) * N + n0 + c];
        tile[r][c] = tv[0]; tile[r][c + 1] = tv[1];
        tile[r][c + 2] = tv[2]; tile[r][c + 3] = tv[3];
    }
    __syncthreads();
#pragma unroll
    for (int st = 0; st < 2; st++) {
        int li = st * 2048 + tid * 8;
        int r = li >> 6, c = li & 63;
        short8 o;
#pragma unroll
        for (int i = 0; i < 8; i++) o[i] = f2bf(tile[c + i][r]);
        *(short8*)&dst[(long)(n0 + r) * Kd + k0 + c] = o;
    }
}

// ---------------- GEMM: C[M][N] = A[M][Kd] @ Bt[N][Kd]^T + bias (+gelu)(+resid) ----------------
template <int BM, bool GELU_ACT, bool OUT_BF16, bool RESID>
__global__ __launch_bounds__(256) void gemm_bt(const short* __restrict__ A,
                                               const short* __restrict__ Bt,
                                               const float* __restrict__ bias,
                                               const float* __restrict__ resid,
                                               void* __restrict__ Cout,
                                               int M, int N, int Kd) {
    constexpr int NR = (BM == 128) ? 4 : 2;
    constexpr int LA = BM / 32;          // A staging rounds
    __shared__ short Asm[BM][64];
    __shared__ short Bsm[128][64];
    const int tid = threadIdx.x;
    const int wid = tid >> 6, lane = tid & 63;
    const int lr = lane & 15, lg = lane >> 4;
    const int row0 = blockIdx.x * BM, col0 = blockIdx.y * 128;
    const int wm = (BM == 128) ? (wid >> 1) * 64 : 0;
    const int wn = (BM == 128) ? (wid & 1) * 64 : wid * 32;

    f32x4 acc[4][NR];
#pragma unroll
    for (int m = 0; m < 4; m++)
#pragma unroll
        for (int n = 0; n < NR; n++)
#pragma unroll
            for (int j = 0; j < 4; j++) acc[m][n][j] = 0.f;

    const int swr = (lr & 7) << 3;   // frag-read column swizzle

    for (int k0 = 0; k0 < Kd; k0 += 64) {
#pragma unroll
        for (int ld = 0; ld < LA; ld++) {
            int off = ld * 2048 + tid * 8;
            int r = off >> 6, c = off & 63;
            int sc = c ^ ((r & 7) << 3);
            gload16(&A[(long)(row0 + r) * Kd + k0 + sc], &Asm[0][0] + off);
        }
#pragma unroll
        for (int ld = 0; ld < 4; ld++) {
            int off = ld * 2048 + tid * 8;
            int r = off >> 6, c = off & 63;
            int sc = c ^ ((r & 7) << 3);
            gload16(&Bt[(long)(col0 + r) * Kd + k0 + sc], &Bsm[0][0] + off);
        }
        __syncthreads();   // drains vmcnt -> LDS tiles ready
#pragma unroll
        for (int kk = 0; kk < 64; kk += 32) {
            short8 af[4], bf[NR];
#pragma unroll
            for (int m = 0; m < 4; m++) af[m] = *(const short8*)&Asm[wm + m * 16 + lr][(kk + lg * 8) ^ swr];
#pragma unroll
            for (int n = 0; n < NR; n++) bf[n] = *(const short8*)&Bsm[wn + n * 16 + lr][(kk + lg * 8) ^ swr];
#pragma unroll
            for (int m = 0; m < 4; m++)
#pragma unroll
                for (int n = 0; n < NR; n++)
                    acc[m][n] = __builtin_amdgcn_mfma_f32_16x16x32_bf16(af[m], bf[n], acc[m][n], 0, 0, 0);
        }
        __syncthreads();
    }

#pragma unroll
    for (int m = 0; m < 4; m++) {
#pragma unroll
        for (int n = 0; n < NR; n++) {
#pragma unroll
            for (int j = 0; j < 4; j++) {
                int r = row0 + wm + m * 16 + lg * 4 + j;
                int c = col0 + wn + n * 16 + lr;
                float v = acc[m][n][j] + bias[c];
                if constexpr (GELU_ACT) v = gelu_f(v);
                if constexpr (RESID) v += resid[(long)r * N + c];
                if constexpr (OUT_BF16) ((short*)Cout)[(long)r * N + c] = f2bf(v);
                else                    ((float*)Cout)[(long)r * N + c] = v;
            }
        }
    }
}

// ---------------- Flash attention v8: 32x32 MFMA, in-register softmax + P ----------------
// v7 with two fixes: (1) cross-half max/sum combines via __shfl_xor(x,32)
// (v7's self-operand permlane could coalesce both "+v" operands into one reg ->
// self-swap, mn inconsistent across hi-halves -> absmax ~35); (2) "memory"
// clobber on the lgkmcnt wait so Vsm ds_writes can't sink past barrier B.
__global__ __launch_bounds__(256) void attn_kernel(const short* __restrict__ q,
                                                   const short* __restrict__ k,
                                                   const short* __restrict__ v,
                                                   float* __restrict__ opart,
                                                   float* __restrict__ mpart,
                                                   float* __restrict__ lpart) {
    __shared__ short Ksm[2][128][64];    // [buf][key][d ^ ((key&7)<<3)]
    __shared__ short Vsm[64][136];       // [d][key ^ ((d>>3)<<3)] (transposed)
    const int tid = threadIdx.x, wid = tid >> 6, lane = tid & 63;
    const int lo = lane & 31, hi = lane >> 5;
    const int bh = blockIdx.y, b = bh >> 3, h = bh & 7;
    const int t0 = blockIdx.x * 128;
    const int split = blockIdx.z;
    const int s_begin = split * 2048;
    const long base = (long)b * 4096 * 1536 + h * 64;

    // Q B-frags (col = q = lo, k-elems d = s*16 + hi*8 ..+8), pre-scaled 0.125*log2e
    short8 qb[4];
    {
        const long qrow = base + (long)(t0 + wid * 32 + lo) * 1536;
#pragma unroll
        for (int s = 0; s < 4; s++) {
            short8 t = *(const short8*)&q[qrow + s * 16 + hi * 8];
#pragma unroll
            for (int i = 0; i < 8; i++) t[i] = f2bf(bf2f(t[i]) * 0.18033688f);
            qb[s] = t;
        }
    }

    f32x16 o0, o1;
#pragma unroll
    for (int i = 0; i < 16; i++) { o0[i] = 0.f; o1[i] = 0.f; }
    float mn = -1e30f, lsum = 0.f;

    const int skey = tid >> 3, sd = (tid & 7) * 8, sm = tid & 7;
    short8 vreg[4];
    // prologue: K tile0 via DMA into buf0; V tile0 into regs
#pragma unroll
    for (int it = 0; it < 4; it++) {
        int off = it * 2048 + tid * 8;
        int r = off >> 6, cc = off & 63;
        int sc = cc ^ ((r & 7) << 3);
        gload16(&k[base + (long)(s_begin + r) * 1536 + sc], &Ksm[0][0][0] + off);
    }
#pragma unroll
    for (int p = 0; p < 4; p++)
        vreg[p] = *(const short8*)&v[base + (long)(s_begin + p * 32 + skey) * 1536 + sd];

    for (int tile = 0; tile < 16; tile++) {
        const int cur = tile & 1;
        __builtin_amdgcn_s_barrier();    // all waves done reading Vsm / Ksm[cur^1]
        // store vreg -> Vsm (compiler's vmcnt wait here also drains Ksm[cur] DMA)
#pragma unroll
        for (int p = 0; p < 4; p++) {
            int key = p * 32 + skey;
            int kc = key ^ (sm << 3);
#pragma unroll
            for (int i = 0; i < 8; i++) Vsm[sd + i][kc] = vreg[p][i];
        }
        // issue next tile: K DMA -> buf^1, V -> regs (fly during compute)
        if (tile + 1 < 16) {
            const int s0n = s_begin + (tile + 1) * 128;
#pragma unroll
            for (int it = 0; it < 4; it++) {
                int off = it * 2048 + tid * 8;
                int r = off >> 6, cc = off & 63;
                int sc = cc ^ ((r & 7) << 3);
                gload16(&k[base + (long)(s0n + r) * 1536 + sc], &Ksm[cur ^ 1][0][0] + off);
            }
#pragma unroll
            for (int p = 0; p < 4; p++)
                vreg[p] = *(const short8*)&v[base + (long)(s0n + p * 32 + skey) * 1536 + sd];
        }
        asm volatile("s_waitcnt lgkmcnt(0)" ::: "memory");
        __builtin_amdgcn_sched_barrier(0);
        __builtin_amdgcn_s_barrier();    // Vsm visible; Ksm[cur] landed (drained above)

        // ---- compute tile from Ksm[cur], Vsm: 4 key-chunks of 32 ----
#pragma unroll
        for (int c = 0; c < 4; c++) {
            const int key = c * 32 + lo;
            const int kx = (key & 7) << 3;
            const short* kp = &Ksm[cur][key][0];
            f32x16 sa;
#pragma unroll
            for (int i = 0; i < 16; i++) sa[i] = 0.f;
            __builtin_amdgcn_s_setprio(1);
#pragma unroll
            for (int s = 0; s < 4; s++) {
                short8 ka = *(const short8*)&kp[(s * 16 + hi * 8) ^ kx];
                sa = __builtin_amdgcn_mfma_f32_32x32x16_bf16(ka, qb[s], sa, 0, 0, 0);
            }
            __builtin_amdgcn_s_setprio(0);

            // in-lane max over 16 keys, combine across hi-halves (safe shfl)
            float cm = fmaxf(sa[0], sa[1]);
#pragma unroll
            for (int i = 2; i < 16; i++) cm = fmaxf(cm, sa[i]);
            cm = fmaxf(cm, __shfl_xor(cm, 32));
            if (!__all(cm <= mn + 8.0f)) {    // defer-max THR=8 (log2 domain)
                float nm = fmaxf(mn, cm);
                float alpha = exp2_fast(mn - nm);
                mn = nm; lsum *= alpha;
#pragma unroll
                for (int r = 0; r < 16; r++) {
                    int qr = (r & 3) + 8 * (r >> 2) + 4 * hi;
                    float ar = __shfl(alpha, qr);
                    o0[r] *= ar; o1[r] *= ar;
                }
            }
            float ls = 0.f;
#pragma unroll
            for (int r = 0; r < 16; r++) {
                float e = exp2_fast(sa[r] - mn);
                sa[r] = e; ls += e;
            }
            lsum += ls;

            // pack P -> bf16 pairs (keys increasing) and build PV A-frags via swaps
            unsigned w0 = cvt_pk_bf16(sa[0], sa[1]),   w1 = cvt_pk_bf16(sa[2], sa[3]);
            unsigned w2 = cvt_pk_bf16(sa[4], sa[5]),   w3 = cvt_pk_bf16(sa[6], sa[7]);
            unsigned w4 = cvt_pk_bf16(sa[8], sa[9]),   w5 = cvt_pk_bf16(sa[10], sa[11]);
            unsigned w6 = cvt_pk_bf16(sa[12], sa[13]), w7 = cvt_pk_bf16(sa[14], sa[15]);
            permlane32_swap(w0, w2);   // -> (frag0 word0, frag0 word2)
            permlane32_swap(w1, w3);   // -> (frag0 word1, frag0 word3)
            permlane32_swap(w4, w6);   // -> (frag1 word0, frag1 word2)
            permlane32_swap(w5, w7);   // -> (frag1 word1, frag1 word3)
            union { unsigned u[4]; short8 s8; } pa0, pa1;
            pa0.u[0] = w0; pa0.u[1] = w1; pa0.u[2] = w2; pa0.u[3] = w3;
            pa1.u[0] = w4; pa1.u[1] = w5; pa1.u[2] = w6; pa1.u[3] = w7;

            // PV: k-steps 2c, 2c+1 over both d-chunks
            const int vc = c * 32 + hi * 8;
            const int d0 = lo, d1 = 32 + lo;
            const int vs0 = ((d0 >> 3) & 7) << 3, vs1 = ((d1 >> 3) & 7) << 3;
            __builtin_amdgcn_s_setprio(1);
            {
                short8 vb00 = *(const short8*)&Vsm[d0][vc ^ vs0];
                short8 vb01 = *(const short8*)&Vsm[d0][(vc + 16) ^ vs0];
                o0 = __builtin_amdgcn_mfma_f32_32x32x16_bf16(pa0.s8, vb00, o0, 0, 0, 0);
                o0 = __builtin_amdgcn_mfma_f32_32x32x16_bf16(pa1.s8, vb01, o0, 0, 0, 0);
                short8 vb10 = *(const short8*)&Vsm[d1][vc ^ vs1];
                short8 vb11 = *(const short8*)&Vsm[d1][(vc + 16) ^ vs1];
                o1 = __builtin_amdgcn_mfma_f32_32x32x16_bf16(pa0.s8, vb10, o1, 0, 0, 0);
                o1 = __builtin_amdgcn_mfma_f32_32x32x16_bf16(pa1.s8, vb11, o1, 0, 0, 0);
            }
            __builtin_amdgcn_s_setprio(0);
        }
    }

    // write partials: O rows q = (reg&3)+8*(reg>>2)+4*hi, cols d = dc*32+lo
    const long rowbase = (long)b * 4096 + t0 + wid * 32;
    const long ob = ((long)split * 8192 + rowbase) * 512 + h * 64;
#pragma unroll
    for (int r = 0; r < 16; r++) {
        int qr = (r & 3) + 8 * (r >> 2) + 4 * hi;
        opart[ob + (long)qr * 512 + lo]      = o0[r];
        opart[ob + (long)qr * 512 + 32 + lo] = o1[r];
    }
    lsum += __shfl_xor(lsum, 32);
    if (lane < 32) {
        long idx = ((long)split * 8192 + rowbase + lo) * 8 + h;
        mpart[idx] = mn;
        lpart[idx] = lsum;
    }
}

// ---------------- Split-KV merge: combine 2 partials -> bf16 ctx ----------------
__global__ __launch_bounds__(256) void attn_merge(const float* __restrict__ op,
                                                  const float* __restrict__ mp,
                                                  const float* __restrict__ lp,
                                                  short* __restrict__ ctx) {
    const int wid = threadIdx.x >> 6, lane = threadIdx.x & 63;
    const long row = (long)blockIdx.x * 4 + wid;
    const int c0 = lane * 8, h = c0 >> 6;
    float m0 = mp[row * 8 + h], m1 = mp[(8192 + row) * 8 + h];
    float l0 = lp[row * 8 + h], l1 = lp[(8192 + row) * 8 + h];
    float M = fmaxf(m0, m1);
    float w0 = exp2_fast(m0 - M), w1 = exp2_fast(m1 - M);
    float inv = 1.0f / (w0 * l0 + w1 * l1);
    w0 *= inv; w1 *= inv;
    f32x4 a0 = *(const f32x4*)&op[row * 512 + c0];
    f32x4 a1 = *(const f32x4*)&op[row * 512 + c0 + 4];
    f32x4 b0 = *(const f32x4*)&op[(8192 + row) * 512 + c0];
    f32x4 b1 = *(const f32x4*)&op[(8192 + row) * 512 + c0 + 4];
    short8 o;
#pragma unroll
    for (int i = 0; i < 4; i++) {
        o[i]     = f2bf(w0 * a0[i] + w1 * b0[i]);
        o[4 + i] = f2bf(w0 * a1[i] + w1 * b1[i]);
    }
    *(short8*)&ctx[row * 512 + c0] = o;
}

// ---------------- Orchestration ----------------
extern "C" void kernel_launch(void* const* d_in, const int* in_sizes, int n_in,
                              void* d_out, int out_size, void* d_ws, size_t ws_size,
                              hipStream_t stream) {
    (void)in_sizes; (void)n_in; (void)out_size; (void)ws_size;
    const float* inputs = (const float*)d_in[0];
    const float* ln1_s  = (const float*)d_in[1];
    const float* ln1_o  = (const float*)d_in[2];
    const float* wq     = (const float*)d_in[3];
    const float* bq     = (const float*)d_in[4];
    const float* wk     = (const float*)d_in[5];
    const float* bk     = (const float*)d_in[6];
    const float* wv     = (const float*)d_in[7];
    const float* bv     = (const float*)d_in[8];
    const float* wo     = (const float*)d_in[9];
    const float* bo     = (const float*)d_in[10];
    const float* ln2_s  = (const float*)d_in[11];
    const float* ln2_o  = (const float*)d_in[12];
    const float* w1     = (const float*)d_in[13];
    const float* b1     = (const float*)d_in[14];
    const float* w2     = (const float*)d_in[15];
    const float* b2     = (const float*)d_in[16];
    float* out = (float*)d_out;

    char* p = (char*)d_ws;
    auto alloc = [&](size_t bytes) { void* r = (void*)p; p += (bytes + 255) & ~(size_t)255; return r; };
    short* x1    = (short*)alloc((size_t)8192 * 512 * 2);
    short* qkvb  = (short*)alloc((size_t)8192 * 1536 * 2);
    short* ctxb  = (short*)alloc((size_t)8192 * 512 * 2);
    short* yb    = (short*)alloc((size_t)8192 * 512 * 2);
    short* hb    = (short*)alloc((size_t)8192 * 2048 * 2);
    short* wqkvt = (short*)alloc((size_t)1536 * 512 * 2);
    short* wot   = (short*)alloc((size_t)512 * 512 * 2);
    short* w1t   = (short*)alloc((size_t)2048 * 512 * 2);
    short* w2t   = (short*)alloc((size_t)512 * 2048 * 2);
    float* bqkv  = (float*)alloc((size_t)1536 * 4);
    float* opart = (float*)alloc((size_t)2 * 8192 * 512 * 4);
    float* mpart = (float*)alloc((size_t)2 * 8192 * 8 * 4);
    float* lpart = (float*)alloc((size_t)2 * 8192 * 8 * 4);

    dim3 blk(256);
    prep_kernel<<<769, blk, 0, stream>>>(wq, wk, wv, wo, w1, w2, bq, bk, bv,
                                         wqkvt, wot, w1t, w2t, bqkv);
    ln_kernel<<<2048, blk, 0, stream>>>(inputs, ln1_s, ln1_o, x1);
    // fused QKV GEMM (128x128 tiles, 768 blocks)
    gemm_bt<128, false, true, false><<<dim3(64, 12), blk, 0, stream>>>(x1, wqkvt, bqkv, nullptr, qkvb, 8192, 1536, 512);
    // attention: split-KV partials + merge
    attn_kernel<<<dim3(32, 16, 2), blk, 0, stream>>>(qkvb, qkvb + 512, qkvb + 1024, opart, mpart, lpart);
    attn_merge<<<2048, blk, 0, stream>>>(opart, mpart, lpart, ctxb);
    // out-proj + residual -> x (fp32, in d_out); 64x128 tiles -> 512 blocks
    gemm_bt<64, false, false, true><<<dim3(128, 4), blk, 0, stream>>>(ctxb, wot, bo, inputs, out, 8192, 512, 512);
    ln_kernel<<<2048, blk, 0, stream>>>(out, ln2_s, ln2_o, yb);
    // FFN1 + GELU (128x128 tiles, 1024 blocks)
    gemm_bt<128, true, true, false><<<dim3(64, 16), blk, 0, stream>>>(yb, w1t, b1, nullptr, hb, 8192, 2048, 512);
    // FFN2 + residual -> out; 64x128 tiles -> 512 blocks
    gemm_bt<64, false, false, true><<<dim3(128, 4), blk, 0, stream>>>(hb, w2t, b2, out, out, 8192, 512, 2048);
}